// Round 10
// baseline (127.063 us; speedup 1.0000x reference)
//
#include <hip/hip_runtime.h>

typedef float v4f __attribute__((ext_vector_type(4)));

#define IMG_H 1080
#define IMG_W 1920
#define NBATCH 8
#define LSTRIP 9             // output rows per lane
#define BROWS (4*LSTRIP)     // 36 rows per block
#define NK (LSTRIP+4)        // 13 schedule rows
#define PF 2                 // prefetch distance (rows ahead)
#define RS 2                 // raw-row ring slots (consume-first: RS>=PF ok)
#define PXL 8                // output px per lane

// R18: R17's 8-px/lane geometry with the ring-clobber fixed. R17 failed
// because with PF=2,RS=2 the prefetch slot (k+PF)%RS == k%RS and the
// prefetch was ISSUED BEFORE the consume -> each iter overwrote the row
// it was about to read (violated RS>=PF+1 for that ordering). Fix:
// consume-first ordering (window-read into locals, THEN prefetch into
// the freed slot) which only needs RS>=PF. Geometry experiment now
// actually runs: 10 positions per 8 outputs = 1.25x/px overlap (vs
// 1.5x at 4px), machinery + edge selects halve per px, wave count
// halves (3840). ~3660 VALU instr/wave measured at 4px vs ~29/px
// algebra floor -> expect ~20-25% static cut. launch_bounds(256,2):
// 256-VGPR budget (est ~220-240), 2 waves/SIMD cap safe (R12 null).
// Spill tripwire: FETCH ~44MB / WRITE 64.8MB must not balloon.
// Edge algebra identical to validated R16, widened 4->8 cols.

__global__ __launch_bounds__(256, 2)
void shi_tomasi_kernel(const float* __restrict__ img, float* __restrict__ out) {
    const int cg    = threadIdx.x & 63;            // lane within wave
    const int strip = threadIdx.x >> 6;            // wave-uniform 0..3
    const int bx    = blockIdx.x;                  // 0..3
    const int c0    = bx * 480 + PXL * (cg - 2);   // output col (lanes 2..61)
    // four aligned dwordx4 loads cover window z[c0-2 .. c0+9] (12 px)
    const int clA   = min(max(c0 - 4, 0), IMG_W - 4);
    const int clB   = min(max(c0,     0), IMG_W - 4);
    const int clC   = min(max(c0 + 4, 0), IMG_W - 4);
    const int clD   = min(max(c0 + 8, 0), IMG_W - 4);
    const int s0    = blockIdx.y * BROWS + strip * LSTRIP;
    const float* g  = img + (size_t)blockIdx.z * (IMG_H * IMG_W);
    float* outb     = out + (size_t)blockIdx.z * (IMG_H * IMG_W);

    const bool eL     = (bx == 0) && (cg == 2);    // c0 == 0
    const bool eR     = (bx == 3) && (cg == 61);   // c0 == W-8
    const bool doSt   = (cg >= 2) && (cg < 62);
    const bool topFix = (s0 == 0);                 // wave-uniform
    const bool botFix = (s0 + LSTRIP == IMG_H);    // wave-uniform

    const float* lpA = g + clA;
    const float* lpB = g + clB;
    const float* lpC = g + clC;
    const float* lpD = g + clD;

    // ---- prologue: rows s0-2, s0-1 into ring slots 0,1 ----
    v4f zA[RS], zB[RS], zC[RS], zD[RS];
    #pragma unroll
    for (int k = 0; k < PF; ++k) {
        const size_t ro = (size_t)max(0, s0 - 2 + k) * IMG_W;
        zA[k % RS] = *(const v4f*)(lpA + ro);
        zB[k % RS] = *(const v4f*)(lpB + ro);
        zC[k % RS] = *(const v4f*)(lpC + ro);
        zD[k % RS] = *(const v4f*)(lpD + ro);
    }

    float cdR[3][10], hsR[3][10];                  // col-diff / col-smooth rings
    float hxx[3][8], hyy[3][8], hxy[3][8];         // horiz box-sum rings

    #pragma unroll
    for (int k = 0; k < NK; ++k) {
        // ---- CONSUME FIRST: read slot k%RS into locals ----
        const v4f A = zA[k % RS];                  // interior: z[-4..-1]
        const v4f B = zB[k % RS];                  // z[0..3]
        const v4f C = zC[k % RS];                  // z[4..7]
        const v4f D = zD[k % RS];                  // interior: z[8..11]

        // ---- then prefetch row k+PF into the freed slot ----
        if (k + PF < NK) {
            const size_t ro = (size_t)min(IMG_H - 1, s0 + k) * IMG_W;  // s0-2+k+PF
            zA[k % RS] = *(const v4f*)(lpA + ro);
            zB[k % RS] = *(const v4f*)(lpB + ro);
            zC[k % RS] = *(const v4f*)(lpC + ro);
            zD[k % RS] = *(const v4f*)(lpD + ro);
        }

        // ---- 12-px scalar window with edge replication ----
        {
            // eL lane: A==B (clamped) -> replicate col 0: z-2=z-1=z0
            // eR lane: D==C (clamped) -> replicate col W-1: z8=z9=z7
            float zw[12];
            zw[0]  = eL ? B.x : A.z;               // z[-2]
            zw[1]  = eL ? B.x : A.w;               // z[-1]
            zw[2]  = B.x; zw[3] = B.y; zw[4] = B.z; zw[5] = B.w;   // z[0..3]
            zw[6]  = C.x; zw[7] = C.y; zw[8] = C.z; zw[9] = C.w;   // z[4..7]
            zw[10] = eR ? C.w : D.x;               // z[8]
            zw[11] = eR ? C.w : D.y;               // z[9]

            float* cdw = cdR[k % 3];
            float* hsw = hsR[k % 3];
            #pragma unroll
            for (int i = 0; i < 10; ++i) {         // i <-> col p = i-1
                cdw[i] = zw[i + 2] - zw[i];
                hsw[i] = fmaf(2.0f, zw[i + 1], zw[i]) + zw[i + 2];
            }
        }

        // ---- product row vr = s0-1+(k-2) (k>=2) ----
        if (k >= 2) {
            const int rr = k - 2;
            const int sm = rr % 3, sz = (rr + 1) % 3, sp = (rr + 2) % 3;

            float Ix[10], Iy[10];
            #pragma unroll
            for (int p = 0; p < 10; ++p) {
                Ix[p] = fmaf(2.0f, cdR[sz][p], cdR[sm][p]) + cdR[sp][p];
                Iy[p] = hsR[sp][p] - hsR[sm][p];
            }
            // field replication at image borders (== validated R16 path)
            if (eL) { Ix[0] = Ix[1]; Iy[0] = Iy[1]; }
            if (eR) { Ix[9] = Ix[8]; Iy[9] = Iy[8]; }

            float xx[10], yy[10], xy[10];
            #pragma unroll
            for (int p = 0; p < 10; ++p) {
                xx[p] = Ix[p] * Ix[p];
                yy[p] = Iy[p] * Iy[p];
                xy[p] = Ix[p] * Iy[p];
            }
            {
                float* hx = hxx[rr % 3];
                float* hy = hyy[rr % 3];
                float* hz = hxy[rr % 3];
                #pragma unroll
                for (int c = 0; c < 8; ++c) {
                    hx[c] = (xx[c] + xx[c + 1]) + xx[c + 2];
                    hy[c] = (yy[c] + yy[c + 1]) + yy[c + 2];
                    hz[c] = (xy[c] + xy[c + 1]) + xy[c + 2];
                }
            }
            if (rr == 1 && topFix) {               // P(-1) == P(0)
                #pragma unroll
                for (int c = 0; c < 8; ++c) {
                    hxx[0][c] = hxx[1][c]; hyy[0][c] = hyy[1][c]; hxy[0][c] = hxy[1][c];
                }
            }
            if (rr == LSTRIP + 1 && botFix) {      // P(H) == P(H-1)
                #pragma unroll
                for (int c = 0; c < 8; ++c) {
                    hxx[rr % 3][c] = hxx[(rr - 1) % 3][c];
                    hyy[rr % 3][c] = hyy[(rr - 1) % 3][c];
                    hxy[rr % 3][c] = hxy[(rr - 1) % 3][c];
                }
            }

            if (rr >= 2) {
                const int a = (rr - 2) % 3, b2 = (rr - 1) % 3, cc = rr % 3;
                float rv[8];
                #pragma unroll
                for (int c = 0; c < 8; ++c) {
                    const float sxx = (hxx[a][c] + hxx[b2][c]) + hxx[cc][c];
                    const float syy = (hyy[a][c] + hyy[b2][c]) + hyy[cc][c];
                    const float sxy = (hxy[a][c] + hxy[b2][c]) + hxy[cc][c];
                    const float S = sxx + syy;
                    const float Dd = sxx - syy;
                    const float E = sxy + sxy;
                    const float disc = fmaf(Dd, Dd, fmaf(E, E, 4e-10f));
                    const float q = __builtin_sqrtf(disc);
                    rv[c] = fmaxf((S - q) * 0.5f, 0.0f);
                }
                if (doSt) {
                    float* orowp = outb + (size_t)(s0 + rr - 2) * IMG_W + c0;
                    __builtin_nontemporal_store(v4f{rv[0], rv[1], rv[2], rv[3]},
                                                (v4f*)orowp);
                    __builtin_nontemporal_store(v4f{rv[4], rv[5], rv[6], rv[7]},
                                                (v4f*)(orowp + 4));
                }
            }
        }
    }
}

extern "C" void kernel_launch(void* const* d_in, const int* in_sizes, int n_in,
                              void* d_out, int out_size, void* d_ws, size_t ws_size,
                              hipStream_t stream) {
    const float* img = (const float*)d_in[0];
    float* out = (float*)d_out;
    dim3 grid(4, IMG_H / BROWS, NBATCH);           // 4 x 30 x 8 = 960 blocks
    shi_tomasi_kernel<<<grid, 256, 0, stream>>>(img, out);
}

// Round 11
// 115.468 us; speedup vs baseline: 1.1004x; 1.1004x over previous
//
#include <hip/hip_runtime.h>

typedef float v4f __attribute__((ext_vector_type(4)));

#define IMG_H 1080
#define IMG_W 1920
#define NBATCH 8
#define LSTRIP 9             // output rows per lane
#define BROWS (4*LSTRIP)     // 36 rows per block
#define NK (LSTRIP+4)        // 13 schedule rows
#define PF 3                 // prefetch distance (rows ahead)
#define RS 4                 // raw-row ring slots (PF+1)

// R19: "unshackle the register allocator" — R16/R18 post-mortem: measured
// ~508 VALU instr/row vs ~250 algebra; steady-state live set ~110 floats
// vs VGPR=60 allocated with ZERO spill (WRITE == exactly 64800KB) ->
// the backend serialized the unrolled 13-row DAG to shrink live ranges
// (consume-after-produce + mov shuffling), destroying the ILP that hides
// 4-8cy VALU dep latency. Explains the whole series: ~50% VALUBusy at
// ~2.4 eff waves/SIMD (R8-R16 invariant), R8's no-memory-waits null,
// R13's spill at 84 regs (pressure TARGETING, not budget), R18's mov
// bloat. Lever: amdgpu_waves_per_eu(1,2) — min 1 wave/EU (512-reg
// legality), max 2 (scheduler stops squeezing for occupancy) -> register-
// fat, latency-optimal schedule. Code is BYTE-IDENTICAL to validated R16
// (42.4us best) except this attribute. Tell: VGPR 60 -> 110+. Tripwire:
// WRITE must stay 64800KB (no spill).

__global__ __attribute__((amdgpu_waves_per_eu(1, 2))) __launch_bounds__(256)
void shi_tomasi_kernel(const float* __restrict__ img, float* __restrict__ out) {
    const int cg    = threadIdx.x & 63;            // lane within wave
    const int strip = threadIdx.x >> 6;            // wave-uniform 0..3
    const int bx    = blockIdx.x;
    const int base  = bx * 240;
    const int c0    = base + 4 * (cg - 2);         // output col (lanes 2..61)
    const int clA   = min(max(c0 - 2, 0), IMG_W - 4);  // left-halo load col
    const int clB   = min(max(c0 + 2, 0), IMG_W - 4);  // right-halo load col
    const int s0    = blockIdx.y * BROWS + strip * LSTRIP;
    const float* g  = img + (size_t)blockIdx.z * (IMG_H * IMG_W);
    float* outb     = out + (size_t)blockIdx.z * (IMG_H * IMG_W);

    const bool eL     = (bx == 0) && (cg == 2);    // c0 == 0
    const bool eR     = (bx == 7) && (cg == 61);   // c0 == W-4
    const bool doSt   = (cg >= 2) && (cg < 62);
    const bool topFix = (s0 == 0);                 // wave-uniform
    const bool botFix = (s0 + LSTRIP == IMG_H);    // wave-uniform

    const float* lpA = g + clA;
    const float* lpB = g + clB;

    // ---- prologue: rows s0-2 .. s0 into ring slots 0..PF-1 ----
    v4f za[RS], zb[RS];
    #pragma unroll
    for (int k = 0; k < PF; ++k) {
        int lr = max(0, min(IMG_H - 1, s0 - 2 + k));
        za[k] = *(const v4f*)(lpA + (size_t)lr * IMG_W);
        zb[k] = *(const v4f*)(lpB + (size_t)lr * IMG_W);
    }

    float cdR[3][6], hsR[3][6];                    // col-diff / col-smooth rings
    float hxx[3][4], hyy[3][4], hxy[3][4];         // horiz box-sum rings

    #pragma unroll
    for (int k = 0; k < NK; ++k) {
        // ---- rolling prefetch: row k+PF (lr = s0-2+k+PF >= 1, no max) ----
        if (k + PF < NK) {
            int lr = min(IMG_H - 1, s0 + k + (PF - 2));
            za[(k + PF) % RS] = *(const v4f*)(lpA + (size_t)lr * IMG_W);
            zb[(k + PF) % RS] = *(const v4f*)(lpB + (size_t)lr * IMG_W);
        }

        // ---- 8-px scalar window with edge replication ----
        {
            const v4f A = za[k % RS];              // interior: z[-2..1]
            const v4f B = zb[k % RS];              // interior: z[2..5]
            // eL lane: A = img[0..4) -> replicate col 0 (z-2=z-1=z0)
            // eR lane: B = img[W-4..W) -> replicate col W-1 (z4=z5=z3)
            const float zm2 = A.x;                 // eL: A.x == z0 (free)
            const float zm1 = eL ? A.x : A.y;
            const float z0  = eL ? A.x : A.z;
            const float z1  = eL ? A.y : A.w;
            const float z2  = eR ? B.z : B.x;
            const float z3  = eR ? B.w : B.y;
            const float z4  = eR ? B.w : B.z;
            const float z5  = B.w;                 // eR: B.w == z3-rep (free)

            float* cdw = cdR[k % 3];
            float* hsw = hsR[k % 3];
            cdw[0] = z0 - zm2;                     // coldiff at p = -1..4
            cdw[1] = z1 - zm1;
            cdw[2] = z2 - z0;
            cdw[3] = z3 - z1;
            cdw[4] = z4 - z2;
            cdw[5] = z5 - z3;
            hsw[0] = fmaf(2.0f, zm1, zm2) + z0;    // colsmooth at p = -1..4
            hsw[1] = fmaf(2.0f, z0, zm1) + z1;
            hsw[2] = fmaf(2.0f, z1, z0) + z2;
            hsw[3] = fmaf(2.0f, z2, z1) + z3;
            hsw[4] = fmaf(2.0f, z3, z2) + z4;
            hsw[5] = fmaf(2.0f, z4, z3) + z5;
        }

        // ---- product row vr = s0-1+(k-2) (k>=2) ----
        if (k >= 2) {
            const int rr = k - 2;
            const int sm = rr % 3, sz = (rr + 1) % 3, sp = (rr + 2) % 3;

            float Ix[6], Iy[6];
            #pragma unroll
            for (int p = 0; p < 6; ++p) {
                Ix[p] = fmaf(2.0f, cdR[sz][p], cdR[sm][p]) + cdR[sp][p];
                Iy[p] = hsR[sp][p] - hsR[sm][p];
            }
            // field replication at image borders (== validated hfd/hfs path)
            if (eL) { Ix[0] = Ix[1]; Iy[0] = Iy[1]; }
            if (eR) { Ix[5] = Ix[4]; Iy[5] = Iy[4]; }

            float xx[6], yy[6], xy[6];
            #pragma unroll
            for (int p = 0; p < 6; ++p) {
                xx[p] = Ix[p] * Ix[p];
                yy[p] = Iy[p] * Iy[p];
                xy[p] = Ix[p] * Iy[p];
            }
            {
                float* hx = hxx[rr % 3];
                float* hy = hyy[rr % 3];
                float* hz = hxy[rr % 3];
                #pragma unroll
                for (int c = 0; c < 4; ++c) {
                    hx[c] = (xx[c] + xx[c + 1]) + xx[c + 2];
                    hy[c] = (yy[c] + yy[c + 1]) + yy[c + 2];
                    hz[c] = (xy[c] + xy[c + 1]) + xy[c + 2];
                }
            }
            if (rr == 1 && topFix) {               // P(-1) == P(0)
                #pragma unroll
                for (int c = 0; c < 4; ++c) {
                    hxx[0][c] = hxx[1][c]; hyy[0][c] = hyy[1][c]; hxy[0][c] = hxy[1][c];
                }
            }
            if (rr == LSTRIP + 1 && botFix) {      // P(H) == P(H-1)
                #pragma unroll
                for (int c = 0; c < 4; ++c) {
                    hxx[rr % 3][c] = hxx[(rr - 1) % 3][c];
                    hyy[rr % 3][c] = hyy[(rr - 1) % 3][c];
                    hxy[rr % 3][c] = hxy[(rr - 1) % 3][c];
                }
            }

            if (rr >= 2) {
                const int a = (rr - 2) % 3, b2 = (rr - 1) % 3, cc = rr % 3;
                float rv[4];
                #pragma unroll
                for (int c = 0; c < 4; ++c) {
                    const float sxx = (hxx[a][c] + hxx[b2][c]) + hxx[cc][c];
                    const float syy = (hyy[a][c] + hyy[b2][c]) + hyy[cc][c];
                    const float sxy = (hxy[a][c] + hxy[b2][c]) + hxy[cc][c];
                    const float S = sxx + syy;
                    const float D = sxx - syy;
                    const float E = sxy + sxy;
                    const float disc = fmaf(D, D, fmaf(E, E, 4e-10f));
                    const float q = __builtin_sqrtf(disc);
                    rv[c] = fmaxf((S - q) * 0.5f, 0.0f);
                }
                if (doSt) {
                    float* orowp = outb + (size_t)(s0 + rr - 2) * IMG_W + c0;
                    __builtin_nontemporal_store(v4f{rv[0], rv[1], rv[2], rv[3]},
                                                (v4f*)orowp);
                }
            }
        }
    }
}

extern "C" void kernel_launch(void* const* d_in, const int* in_sizes, int n_in,
                              void* d_out, int out_size, void* d_ws, size_t ws_size,
                              hipStream_t stream) {
    const float* img = (const float*)d_in[0];
    float* out = (float*)d_out;
    dim3 grid(8, IMG_H / BROWS, NBATCH);           // 8 x 30 x 8 = 1920 blocks
    shi_tomasi_kernel<<<grid, 256, 0, stream>>>(img, out);
}

// Round 12
// 114.062 us; speedup vs baseline: 1.1140x; 1.0123x over previous
//
#include <hip/hip_runtime.h>

typedef float v4f __attribute__((ext_vector_type(4)));

#define IMG_H 1080
#define IMG_W 1920
#define NBATCH 8
#define LSTRIP 9             // output rows per lane
#define BROWS (4*LSTRIP)     // 36 rows per block
#define NK (LSTRIP+4)        // 13 schedule rows
#define PF 3                 // prefetch distance (rows ahead)
#define RS 4                 // raw-row ring slots (PF+1)

// R20: "raw sqrt — isolate the libm tail". R19 falsified the register-
// pressure/serialization theory (VGPR 60->88, dur flat 43.8). Remaining
// never-isolated instruction fat: __builtin_sqrtf compiles to the IEEE
// guarded sequence (~8-10 instr: scale + v_sqrt_f32 + Newton fixup), x4
// per lane-row, on the store-side dep chain = ~25% of static VALU. R15
// bundled raw sqrt with broken VOP3P asm — never tested alone; its
// failure signature (3.8e6, region-scale) matches pk-asm operand
// semantics, not a 1-ulp sqrt (bound here: q<=1.4e7, rel 1e-7 -> abs
// err ~1 << 4096 threshold). This round: BYTE-IDENTICAL validated R16
// (42.4us) + __builtin_amdgcn_sqrtf only. If dur flat, VALU instruction
// count is exonerated entirely -> pivot to memory-latency/LDS-sharing.

__global__ __launch_bounds__(256, 2)
void shi_tomasi_kernel(const float* __restrict__ img, float* __restrict__ out) {
    const int cg    = threadIdx.x & 63;            // lane within wave
    const int strip = threadIdx.x >> 6;            // wave-uniform 0..3
    const int bx    = blockIdx.x;
    const int base  = bx * 240;
    const int c0    = base + 4 * (cg - 2);         // output col (lanes 2..61)
    const int clA   = min(max(c0 - 2, 0), IMG_W - 4);  // left-halo load col
    const int clB   = min(max(c0 + 2, 0), IMG_W - 4);  // right-halo load col
    const int s0    = blockIdx.y * BROWS + strip * LSTRIP;
    const float* g  = img + (size_t)blockIdx.z * (IMG_H * IMG_W);
    float* outb     = out + (size_t)blockIdx.z * (IMG_H * IMG_W);

    const bool eL     = (bx == 0) && (cg == 2);    // c0 == 0
    const bool eR     = (bx == 7) && (cg == 61);   // c0 == W-4
    const bool doSt   = (cg >= 2) && (cg < 62);
    const bool topFix = (s0 == 0);                 // wave-uniform
    const bool botFix = (s0 + LSTRIP == IMG_H);    // wave-uniform

    const float* lpA = g + clA;
    const float* lpB = g + clB;

    // ---- prologue: rows s0-2 .. s0 into ring slots 0..PF-1 ----
    v4f za[RS], zb[RS];
    #pragma unroll
    for (int k = 0; k < PF; ++k) {
        int lr = max(0, min(IMG_H - 1, s0 - 2 + k));
        za[k] = *(const v4f*)(lpA + (size_t)lr * IMG_W);
        zb[k] = *(const v4f*)(lpB + (size_t)lr * IMG_W);
    }

    float cdR[3][6], hsR[3][6];                    // col-diff / col-smooth rings
    float hxx[3][4], hyy[3][4], hxy[3][4];         // horiz box-sum rings

    #pragma unroll
    for (int k = 0; k < NK; ++k) {
        // ---- rolling prefetch: row k+PF (lr = s0-2+k+PF >= 1, no max) ----
        if (k + PF < NK) {
            int lr = min(IMG_H - 1, s0 + k + (PF - 2));
            za[(k + PF) % RS] = *(const v4f*)(lpA + (size_t)lr * IMG_W);
            zb[(k + PF) % RS] = *(const v4f*)(lpB + (size_t)lr * IMG_W);
        }

        // ---- 8-px scalar window with edge replication ----
        {
            const v4f A = za[k % RS];              // interior: z[-2..1]
            const v4f B = zb[k % RS];              // interior: z[2..5]
            // eL lane: A = img[0..4) -> replicate col 0 (z-2=z-1=z0)
            // eR lane: B = img[W-4..W) -> replicate col W-1 (z4=z5=z3)
            const float zm2 = A.x;                 // eL: A.x == z0 (free)
            const float zm1 = eL ? A.x : A.y;
            const float z0  = eL ? A.x : A.z;
            const float z1  = eL ? A.y : A.w;
            const float z2  = eR ? B.z : B.x;
            const float z3  = eR ? B.w : B.y;
            const float z4  = eR ? B.w : B.z;
            const float z5  = B.w;                 // eR: B.w == z3-rep (free)

            float* cdw = cdR[k % 3];
            float* hsw = hsR[k % 3];
            cdw[0] = z0 - zm2;                     // coldiff at p = -1..4
            cdw[1] = z1 - zm1;
            cdw[2] = z2 - z0;
            cdw[3] = z3 - z1;
            cdw[4] = z4 - z2;
            cdw[5] = z5 - z3;
            hsw[0] = fmaf(2.0f, zm1, zm2) + z0;    // colsmooth at p = -1..4
            hsw[1] = fmaf(2.0f, z0, zm1) + z1;
            hsw[2] = fmaf(2.0f, z1, z0) + z2;
            hsw[3] = fmaf(2.0f, z2, z1) + z3;
            hsw[4] = fmaf(2.0f, z3, z2) + z4;
            hsw[5] = fmaf(2.0f, z4, z3) + z5;
        }

        // ---- product row vr = s0-1+(k-2) (k>=2) ----
        if (k >= 2) {
            const int rr = k - 2;
            const int sm = rr % 3, sz = (rr + 1) % 3, sp = (rr + 2) % 3;

            float Ix[6], Iy[6];
            #pragma unroll
            for (int p = 0; p < 6; ++p) {
                Ix[p] = fmaf(2.0f, cdR[sz][p], cdR[sm][p]) + cdR[sp][p];
                Iy[p] = hsR[sp][p] - hsR[sm][p];
            }
            // field replication at image borders (== validated hfd/hfs path)
            if (eL) { Ix[0] = Ix[1]; Iy[0] = Iy[1]; }
            if (eR) { Ix[5] = Ix[4]; Iy[5] = Iy[4]; }

            float xx[6], yy[6], xy[6];
            #pragma unroll
            for (int p = 0; p < 6; ++p) {
                xx[p] = Ix[p] * Ix[p];
                yy[p] = Iy[p] * Iy[p];
                xy[p] = Ix[p] * Iy[p];
            }
            {
                float* hx = hxx[rr % 3];
                float* hy = hyy[rr % 3];
                float* hz = hxy[rr % 3];
                #pragma unroll
                for (int c = 0; c < 4; ++c) {
                    hx[c] = (xx[c] + xx[c + 1]) + xx[c + 2];
                    hy[c] = (yy[c] + yy[c + 1]) + yy[c + 2];
                    hz[c] = (xy[c] + xy[c + 1]) + xy[c + 2];
                }
            }
            if (rr == 1 && topFix) {               // P(-1) == P(0)
                #pragma unroll
                for (int c = 0; c < 4; ++c) {
                    hxx[0][c] = hxx[1][c]; hyy[0][c] = hyy[1][c]; hxy[0][c] = hxy[1][c];
                }
            }
            if (rr == LSTRIP + 1 && botFix) {      // P(H) == P(H-1)
                #pragma unroll
                for (int c = 0; c < 4; ++c) {
                    hxx[rr % 3][c] = hxx[(rr - 1) % 3][c];
                    hyy[rr % 3][c] = hyy[(rr - 1) % 3][c];
                    hxy[rr % 3][c] = hxy[(rr - 1) % 3][c];
                }
            }

            if (rr >= 2) {
                const int a = (rr - 2) % 3, b2 = (rr - 1) % 3, cc = rr % 3;
                float rv[4];
                #pragma unroll
                for (int c = 0; c < 4; ++c) {
                    const float sxx = (hxx[a][c] + hxx[b2][c]) + hxx[cc][c];
                    const float syy = (hyy[a][c] + hyy[b2][c]) + hyy[cc][c];
                    const float sxy = (hxy[a][c] + hxy[b2][c]) + hxy[cc][c];
                    const float S = sxx + syy;
                    const float D = sxx - syy;
                    const float E = sxy + sxy;
                    const float disc = fmaf(D, D, fmaf(E, E, 4e-10f));
                    const float q = __builtin_amdgcn_sqrtf(disc);  // raw v_sqrt_f32
                    rv[c] = fmaxf((S - q) * 0.5f, 0.0f);
                }
                if (doSt) {
                    float* orowp = outb + (size_t)(s0 + rr - 2) * IMG_W + c0;
                    __builtin_nontemporal_store(v4f{rv[0], rv[1], rv[2], rv[3]},
                                                (v4f*)orowp);
                }
            }
        }
    }
}

extern "C" void kernel_launch(void* const* d_in, const int* in_sizes, int n_in,
                              void* d_out, int out_size, void* d_ws, size_t ws_size,
                              hipStream_t stream) {
    const float* img = (const float*)d_in[0];
    float* out = (float*)d_out;
    dim3 grid(8, IMG_H / BROWS, NBATCH);           // 8 x 30 x 8 = 1920 blocks
    shi_tomasi_kernel<<<grid, 256, 0, stream>>>(img, out);
}

// Round 13
// 113.050 us; speedup vs baseline: 1.1240x; 1.0089x over previous
//
#include <hip/hip_runtime.h>

typedef float v2f __attribute__((ext_vector_type(2)));
typedef float v4f __attribute__((ext_vector_type(4)));

#define IMG_H 1080
#define IMG_W 1920
#define NBATCH 8
#define LSTRIP 9             // output rows per lane
#define BROWS (4*LSTRIP)     // 36 rows per block
#define NK (LSTRIP+4)        // 13 schedule rows
#define NROWS 40             // staged rows per block (36 + 4 halo)
#define ROWF 264             // floats per LDS row (256 staged + 8 pad)

// R21: "LDS-staged tile — change the latency class of the consume path".
// Matrix complete: R8/R11/R12/R13/R14/R16/R18/R19/R20 all null at 42-44us.
// R20's tell: cutting ~30% of VALU made profiled dur WORSE (50-55us,
// VALUBusy 54->30) -> a fixed per-row latency event was being hidden by
// compute; every variant consumes HBM loads directly in registers, and
// per-wave prefetch never covers ~900cy HBM latency because waves stall
// in lockstep. Fix (the one untouched axis): block-cooperative LDS tile.
// Each block stages 40 rows x 256 floats (base-8..base+247, per-lane
// clamped cols; rows clamped) via global_load_lds (wave-uniform dest +
// lane*16B = exactly our row layout; source is per-lane), one barrier,
// then 13 compute rows consume from LDS (ds latency ~120cy, 4x b64/row).
// Overfetch: horiz 2x->1.07x, vert 1.44x->1.11x. 42.2KB LDS -> 3
// blocks/CU; staging of one block overlaps compute of others.
// Window mapping re-derived in LDS coords (content(q)=col(base-8+q)):
// interior D0..D3 at float idx 4cg-2.. gives exactly z[-2..5]; edge
// staging clamps make z0..z3 come out interior-correct and only 4
// selects needed: eL zm2/zm1<-D1.x (col0); eR z4/z5<-D2.y (col1919).
// Compute body / rings / top-bot fixes / raw sqrt / store: identical R20.

__global__ __launch_bounds__(256, 2)
void shi_tomasi_kernel(const float* __restrict__ img, float* __restrict__ out) {
    __shared__ float lds[NROWS * ROWF];

    const int cg    = threadIdx.x & 63;            // lane within wave
    const int strip = threadIdx.x >> 6;            // wave-uniform 0..3
    const int bx    = blockIdx.x;
    const int base  = bx * 240;
    const int c0    = base + 4 * (cg - 2);         // output col (lanes 2..61)
    const int S0    = blockIdx.y * BROWS;          // first output row of block
    const int s0    = S0 + strip * LSTRIP;
    const float* g  = img + (size_t)blockIdx.z * (IMG_H * IMG_W);
    float* outb     = out + (size_t)blockIdx.z * (IMG_H * IMG_W);

    const bool eL     = (bx == 0) && (cg == 2);    // c0 == 0
    const bool eR     = (bx == 7) && (cg == 61);   // c0 == W-4
    const bool doSt   = (cg >= 2) && (cg < 62);
    const bool topFix = (s0 == 0);                 // wave-uniform
    const bool botFix = (s0 + LSTRIP == IMG_H);    // wave-uniform

    // per-lane staged column (16B chunk base), clamped & 16B aligned
    const int cl = min(max(base - 8 + 4 * cg, 0), IMG_W - 4);

    // ---- cooperative staging: wave 'strip' stages rows j = strip*10 .. +9 ----
    #pragma unroll
    for (int t = 0; t < 10; ++t) {
        const int j = strip * 10 + t;
        const int r = min(max(S0 - 2 + j, 0), IMG_H - 1);
        __builtin_amdgcn_global_load_lds(
            (const __attribute__((address_space(1))) void*)(g + (size_t)r * IMG_W + cl),
            (__attribute__((address_space(3))) void*)&lds[j * ROWF],
            16, 0, 0);
    }
    __syncthreads();                               // drains vmcnt before barrier

    float cdR[3][6], hsR[3][6];                    // col-diff / col-smooth rings
    float hxx[3][4], hyy[3][4], hxy[3][4];         // horiz box-sum rings

    const int qoff = max(4 * cg - 2, 0);           // window base float in row

    #pragma unroll
    for (int k = 0; k < NK; ++k) {
        // ---- 8-px window from LDS (4x ds_read_b64, 8B aligned) ----
        {
            const float* lr = &lds[(9 * strip + k) * ROWF + qoff];
            const v2f D0 = *(const v2f*)(lr);
            const v2f D1 = *(const v2f*)(lr + 2);
            const v2f D2 = *(const v2f*)(lr + 4);
            const v2f D3 = *(const v2f*)(lr + 6);
            // interior: D0..D3 = cols c0-2..c0+5. Edge fixes (derived from
            // staged clamped content): eL needs zm2=zm1=col0=D1.x (z0..z3
            // already correct); eR needs z4=z5=col1919=D2.y.
            const float zm2 = eL ? D1.x : D0.x;
            const float zm1 = eL ? D1.x : D0.y;
            const float z0  = D1.x;
            const float z1  = D1.y;
            const float z2  = D2.x;
            const float z3  = D2.y;
            const float z4  = eR ? D2.y : D3.x;
            const float z5  = eR ? D2.y : D3.y;

            float* cdw = cdR[k % 3];
            float* hsw = hsR[k % 3];
            cdw[0] = z0 - zm2;                     // coldiff at p = -1..4
            cdw[1] = z1 - zm1;
            cdw[2] = z2 - z0;
            cdw[3] = z3 - z1;
            cdw[4] = z4 - z2;
            cdw[5] = z5 - z3;
            hsw[0] = fmaf(2.0f, zm1, zm2) + z0;    // colsmooth at p = -1..4
            hsw[1] = fmaf(2.0f, z0, zm1) + z1;
            hsw[2] = fmaf(2.0f, z1, z0) + z2;
            hsw[3] = fmaf(2.0f, z2, z1) + z3;
            hsw[4] = fmaf(2.0f, z3, z2) + z4;
            hsw[5] = fmaf(2.0f, z4, z3) + z5;
        }

        // ---- product row vr = s0-1+(k-2) (k>=2) ----
        if (k >= 2) {
            const int rr = k - 2;
            const int sm = rr % 3, sz = (rr + 1) % 3, sp = (rr + 2) % 3;

            float Ix[6], Iy[6];
            #pragma unroll
            for (int p = 0; p < 6; ++p) {
                Ix[p] = fmaf(2.0f, cdR[sz][p], cdR[sm][p]) + cdR[sp][p];
                Iy[p] = hsR[sp][p] - hsR[sm][p];
            }
            // field replication at image borders (== validated hfd/hfs path)
            if (eL) { Ix[0] = Ix[1]; Iy[0] = Iy[1]; }
            if (eR) { Ix[5] = Ix[4]; Iy[5] = Iy[4]; }

            float xx[6], yy[6], xy[6];
            #pragma unroll
            for (int p = 0; p < 6; ++p) {
                xx[p] = Ix[p] * Ix[p];
                yy[p] = Iy[p] * Iy[p];
                xy[p] = Ix[p] * Iy[p];
            }
            {
                float* hx = hxx[rr % 3];
                float* hy = hyy[rr % 3];
                float* hz = hxy[rr % 3];
                #pragma unroll
                for (int c = 0; c < 4; ++c) {
                    hx[c] = (xx[c] + xx[c + 1]) + xx[c + 2];
                    hy[c] = (yy[c] + yy[c + 1]) + yy[c + 2];
                    hz[c] = (xy[c] + xy[c + 1]) + xy[c + 2];
                }
            }
            if (rr == 1 && topFix) {               // P(-1) == P(0)
                #pragma unroll
                for (int c = 0; c < 4; ++c) {
                    hxx[0][c] = hxx[1][c]; hyy[0][c] = hyy[1][c]; hxy[0][c] = hxy[1][c];
                }
            }
            if (rr == LSTRIP + 1 && botFix) {      // P(H) == P(H-1)
                #pragma unroll
                for (int c = 0; c < 4; ++c) {
                    hxx[rr % 3][c] = hxx[(rr - 1) % 3][c];
                    hyy[rr % 3][c] = hyy[(rr - 1) % 3][c];
                    hxy[rr % 3][c] = hxy[(rr - 1) % 3][c];
                }
            }

            if (rr >= 2) {
                const int a = (rr - 2) % 3, b2 = (rr - 1) % 3, cc = rr % 3;
                float rv[4];
                #pragma unroll
                for (int c = 0; c < 4; ++c) {
                    const float sxx = (hxx[a][c] + hxx[b2][c]) + hxx[cc][c];
                    const float syy = (hyy[a][c] + hyy[b2][c]) + hyy[cc][c];
                    const float sxy = (hxy[a][c] + hxy[b2][c]) + hxy[cc][c];
                    const float S = sxx + syy;
                    const float D = sxx - syy;
                    const float E = sxy + sxy;
                    const float disc = fmaf(D, D, fmaf(E, E, 4e-10f));
                    const float q = __builtin_amdgcn_sqrtf(disc);  // raw v_sqrt_f32
                    rv[c] = fmaxf((S - q) * 0.5f, 0.0f);
                }
                if (doSt) {
                    float* orowp = outb + (size_t)(s0 + rr - 2) * IMG_W + c0;
                    __builtin_nontemporal_store(v4f{rv[0], rv[1], rv[2], rv[3]},
                                                (v4f*)orowp);
                }
            }
        }
    }
}

extern "C" void kernel_launch(void* const* d_in, const int* in_sizes, int n_in,
                              void* d_out, int out_size, void* d_ws, size_t ws_size,
                              hipStream_t stream) {
    const float* img = (const float*)d_in[0];
    float* out = (float*)d_out;
    dim3 grid(8, IMG_H / BROWS, NBATCH);           // 8 x 30 x 8 = 1920 blocks
    shi_tomasi_kernel<<<grid, 256, 0, stream>>>(img, out);
}